// Round 5
// baseline (913.954 us; speedup 1.0000x reference)
//
// R5: persistent 2-tile gemm blocks (cross-tile prefetch under epilogue) +
// finalize fused via last-block-per-batch (device-scope counter in ws).
// K-loop untouched (R4 showed it's HBM-pinned).
#include <hip/hip_runtime.h>
#include <hip/hip_bf16.h>
#include <math.h>

#define B_  32
#define T_  4096
#define H_  256
#define D_  512

// ws layout (bytes):
//   pre   : float [32*256]        @ 0
//   we_hi : ushort[256*512]       @ 32768   (bf16 W_e, per-BK-tile + XOR-swizzled)
//   p     : float [32*4096]       @ 294912  (exp(s - m_blk) per row)
//   ml    : float2[1024]          @ 819200  (per-tile m_blk, l_blk)
//   pctx  : float [1024*512]      @ 827392  (per-tile partial context)
//   cnt   : int   [32]            @ 2924544 (per-batch arrival counters)
#define WS_PRE    0
#define WS_WEHI   32768
#define WS_P      294912
#define WS_ML     819200
#define WS_PCTX   827392
#define WS_CNT    2924544

using short8  = __attribute__((ext_vector_type(8))) short;
using float4v = __attribute__((ext_vector_type(4))) float;

__device__ __forceinline__ unsigned cvt2_bf16(float lo, float hi) {
    union { __hip_bfloat162 h; unsigned u; } cv;
    cv.h = __float22bfloat162_rn(make_float2(lo, hi));
    return cv.u;
}
__device__ __forceinline__ short8 cvt8_bf16(const float* a) {
    union { unsigned u[4]; short8 s; } r;
    r.u[0] = cvt2_bf16(a[0], a[1]);
    r.u[1] = cvt2_bf16(a[2], a[3]);
    r.u[2] = cvt2_bf16(a[4], a[5]);
    r.u[3] = cvt2_bf16(a[6], a[7]);
    return r.s;
}

// tanh(x) = 1 - 2/(e^{2x}+1); |err| ~1e-7, far below the bf16 score floor.
__device__ __forceinline__ float fast_tanh(float x) {
    float e = __expf(2.0f * x);
    return 1.0f - 2.0f * __builtin_amdgcn_rcpf(e + 1.0f);
}

// ---------------------------------------------------------------- prep ------
// blocks 0..31 : h_proj + b_attn
// blocks 32..63: W_e -> bf16, TILED per BK=32 (16KB tiles), XOR-swizzled:
//   (n,k): t=k>>5, quad=(k&31)>>3, e=k&7, slot=quad^((n>>1)&3);
//   dst = t*8192 + n*32 + slot*8 + e.
// block 32 also zeroes the per-batch counters (ws is re-poisoned every iter).
__global__ __launch_bounds__(256)
void prep_kernel(const float* __restrict__ hidden,
                 const float* __restrict__ W_attn,
                 const float* __restrict__ b_attn,
                 unsigned char* __restrict__ ws) {
    int blk = blockIdx.x;
    int tid = threadIdx.x;
    if (blk < 32) {
        int b = blk, h = tid;
        const float4* hv = (const float4*)(hidden + b * D_);
        const float4* wv = (const float4*)(W_attn + (size_t)h * 1024);
        float s = 0.f;
        #pragma unroll 4
        for (int d4 = 0; d4 < D_ / 4; ++d4) {
            float4 a = hv[d4], w = wv[d4];
            s += a.x * w.x + a.y * w.y + a.z * w.z + a.w * w.w;
        }
        ((float*)(ws + WS_PRE))[b * H_ + h] = s + b_attn[h];
    } else {
        if (blk == 32 && tid < 32) ((int*)(ws + WS_CNT))[tid] = 0;
        int q = (blk - 32) * 256 + tid;            // 0..8191
        unsigned short* whi = (unsigned short*)(ws + WS_WEHI);
        #pragma unroll
        for (int i = 0; i < 4; ++i) {
            int idx4 = q + i * 8192;               // float4 index over [256][128]
            int n = idx4 >> 7, k = (idx4 & 127) << 2;
            int t = k >> 5, kin = k & 31;
            int quad = kin >> 3, e = kin & 7;      // e in {0,4}
            int slot = quad ^ ((n >> 1) & 3);
            float4 w = *(const float4*)(W_attn + (size_t)n * 1024 + 512 + k);
            unsigned lo = cvt2_bf16(w.x, w.y);
            unsigned hi = cvt2_bf16(w.z, w.w);
            unsigned short* dst = whi + t * 8192 + n * 32 + slot * 8 + e;
            *(uint2*)dst = make_uint2(lo, hi);     // 8B aligned (e in {0,4})
        }
    }
}

// ------------------------------- GEMM + tanh + v-dot + softmax + pctx + fin -
// grid = 512 persistent blocks x 2 tiles (bid, bid+512); 512 threads.
// BM=128 x BN=256 (full N) x K=512, BK=32.
// A: HBM -> regs (2 sets, 2 slabs ahead) -> bf16 -> LDS (double-buffered).
// B: L2-resident ws tiles -> registers, 1 iter ahead.
// Next tile's slab0/1 + B0/1 loads issued during previous tile's softmax.
// Last block to finish a batch (device counter) runs that batch's finalize.
#define BM 128
#define BN 256
#define BK 32
#define LDT 40   // LDS A row stride in ushorts: 80B rows -> 2-way-only alias
#define KIT 16

__global__ __launch_bounds__(512, 4)
void gemm_scores_kernel(const float* __restrict__ enc,
                        unsigned char* __restrict__ ws,
                        const float* __restrict__ v,
                        float* __restrict__ out_ctx,
                        float* __restrict__ out_w) {
    __shared__ unsigned short sA[2][BM * LDT];     // 20480 B (reused by epilogue)
    __shared__ float sScoreP[4][BM];               // partial scores / fin scratch
    __shared__ float sP[BM];
    __shared__ float sRed[4];
    __shared__ int   sLastFlag;

    const float*          pre_all = (const float*)(ws + WS_PRE);
    const unsigned short* weh     = (const unsigned short*)(ws + WS_WEHI);
    int*                  cnt     = (int*)(ws + WS_CNT);

    int tid = threadIdx.x;
    int rowA = tid & 127, cgA = tid >> 7;
    int wave = tid >> 6, lane = tid & 63;
    int wm = wave & 1, wn = wave >> 1;             // 2 x 4 waves, 64x64 tiles
    int quad = lane >> 4, l16 = lane & 15;

    // B fragment base: slot = quad ^ ((c>>1)&3) = quad ^ ((l16>>1)&3)
    int slotB = quad ^ ((l16 >> 1) & 3);
    const unsigned short* bBase = weh + (wn * 64 + l16) * 32 + slotB * 8;

    float aX[8], aY[8];                            // two A prefetch sets
    short8 bhA[4], bhB[4];                         // two B fragment sets

    int tile = blockIdx.x;
    int finBatch[2] = {-1, -1};

    // ---- preload tile0: slab0->aX, slab1->aY, B tile0->bhA, tile1->bhB
    {
        const float* gA0 = enc + (size_t)(tile * BM + rowA) * D_ + cgA * 8;
        const float4* p0 = (const float4*)gA0;
        *(float4*)aX = p0[0]; *(float4*)(aX + 4) = p0[1];
        #pragma unroll
        for (int j = 0; j < 4; ++j) bhA[j] = *(const short8*)(bBase + j * 512);
        const float4* p1 = (const float4*)(gA0 + BK);
        *(float4*)aY = p1[0]; *(float4*)(aY + 4) = p1[1];
        #pragma unroll
        for (int j = 0; j < 4; ++j) bhB[j] = *(const short8*)(bBase + 8192 + j * 512);
    }

    for (int tt = 0; tt < 2; ++tt) {
        int m0 = tile * BM;
        int b  = m0 >> 12;
        const float* gA = enc + (size_t)(m0 + rowA) * D_ + cgA * 8;

        // stage slab0 (regs) into LDS buf0
        *(short8*)&sA[0][rowA * LDT + cgA * 8] = cvt8_bf16(aX);
        __builtin_amdgcn_s_waitcnt(0xc07f);   // lgkmcnt(0) only
        __builtin_amdgcn_s_barrier();

        float4v acc[4][4] = {};

        // One k-step. Bcur = tile kk (loaded last iter); Bnxt <- tile kk+1.
        // Acons = slab kk+1 (LDS-written this iter); Aload <- slab kk+2.
#define K_STEP(kk, CUR, NXT, Acons, Aload, Bcur, Bnxt)                        \
    {                                                                         \
        if ((kk) + 1 < KIT) {                                                 \
            const unsigned short* pb = bBase + ((kk) + 1) * 8192;             \
            Bnxt[0] = *(const short8*)(pb);                                   \
            Bnxt[1] = *(const short8*)(pb + 512);                             \
            Bnxt[2] = *(const short8*)(pb + 1024);                            \
            Bnxt[3] = *(const short8*)(pb + 1536);                            \
        }                                                                     \
        if ((kk) + 2 < KIT) {                                                 \
            const float4* pa = (const float4*)(gA + ((kk) + 2) * BK);         \
            *(float4*)(Aload) = pa[0]; *(float4*)((Aload) + 4) = pa[1];       \
        }                                                                     \
        short8 ah[4];                                                         \
        _Pragma("unroll")                                                     \
        for (int i = 0; i < 4; ++i) {                                         \
            int r = wm * 64 + i * 16 + l16;                                   \
            ah[i] = *(const short8*)&sA[CUR][r * LDT + quad * 8];             \
        }                                                                     \
        _Pragma("unroll")                                                     \
        for (int i = 0; i < 4; ++i)                                           \
            _Pragma("unroll")                                                 \
            for (int j = 0; j < 4; ++j)                                       \
                acc[i][j] = __builtin_amdgcn_mfma_f32_16x16x32_bf16(          \
                    ah[i], Bcur[j], acc[i][j], 0, 0, 0);                      \
        if ((kk) + 1 < KIT) {                                                 \
            *(short8*)&sA[NXT][rowA * LDT + cgA * 8] = cvt8_bf16(Acons);      \
            __builtin_amdgcn_s_waitcnt(0xc07f);                               \
            __builtin_amdgcn_s_barrier();                                     \
        }                                                                     \
    }

        for (int kt = 0; kt < 8; ++kt) {
            K_STEP(2 * kt,     0, 1, aY, aX, bhA, bhB)
            K_STEP(2 * kt + 1, 1, 0, aX, aY, bhB, bhA)
        }
#undef K_STEP

        // ---- scores: energy = tanh(acc + pre[b][n]); rowsum += energy*v[n]
        float rowsum[4][4] = {};
        #pragma unroll
        for (int j = 0; j < 4; ++j) {
            int n = wn * 64 + j * 16 + l16;
            float pv = pre_all[b * H_ + n];
            float vv = v[n];
            #pragma unroll
            for (int i = 0; i < 4; ++i)
                #pragma unroll
                for (int r = 0; r < 4; ++r)
                    rowsum[i][r] += fast_tanh(acc[i][j][r] + pv) * vv;
        }
        #pragma unroll
        for (int i = 0; i < 4; ++i)
            #pragma unroll
            for (int r = 0; r < 4; ++r) {
                float s = rowsum[i][r];
                s += __shfl_xor(s, 1);
                s += __shfl_xor(s, 2);
                s += __shfl_xor(s, 4);
                s += __shfl_xor(s, 8);
                rowsum[i][r] = s;
            }
        if (l16 == 0) {
            #pragma unroll
            for (int i = 0; i < 4; ++i)
                #pragma unroll
                for (int r = 0; r < 4; ++r) {
                    int row = wm * 64 + i * 16 + quad * 4 + r;
                    sScoreP[wn][row] = rowsum[i][r];
                }
        }
        __syncthreads();

        // ---- preload NEXT tile now (acc dead): HBM latency hides under
        // the softmax + context epilogue below.
        if (tt == 0) {
            const float* gAn = enc + (size_t)((tile + 512) * BM + rowA) * D_ + cgA * 8;
            const float4* p0 = (const float4*)gAn;
            *(float4*)aX = p0[0]; *(float4*)(aX + 4) = p0[1];
            #pragma unroll
            for (int j = 0; j < 4; ++j) bhA[j] = *(const short8*)(bBase + j * 512);
            const float4* p1 = (const float4*)(gAn + BK);
            *(float4*)aY = p1[0]; *(float4*)(aY + 4) = p1[1];
            #pragma unroll
            for (int j = 0; j < 4; ++j) bhB[j] = *(const short8*)(bBase + 8192 + j * 512);
        }

        // ---- local softmax over the 128 rows
        float sval = 0.f;
        if (tid < 128) {
            sval = sScoreP[0][tid] + sScoreP[1][tid]
                 + sScoreP[2][tid] + sScoreP[3][tid];
            float m = sval;
            #pragma unroll
            for (int off = 32; off; off >>= 1) m = fmaxf(m, __shfl_xor(m, off));
            if (lane == 0) sRed[wave] = m;
        }
        __syncthreads();
        float m_blk = fmaxf(sRed[0], sRed[1]);
        if (tid < 128) {
            float p = expf(sval - m_blk);
            sP[tid] = p;
            ((float*)(ws + WS_P))[m0 + tid] = p;
            float l = p;
            #pragma unroll
            for (int off = 32; off; off >>= 1) l += __shfl_xor(l, off);
            if (lane == 0) sRed[2 + wave] = l;
        }
        __syncthreads();
        if (tid == 0) {
            float2 ml = make_float2(m_blk, sRed[2] + sRed[3]);
            ((float2*)(ws + WS_ML))[tile] = ml;
        }

        // ---- partial context: re-read own slab (cache-hot), weight by p
        int colg = tid & 127, rgrp = tid >> 7;
        const float* encb = enc + (size_t)m0 * D_;
        float4 c4 = {0.f, 0.f, 0.f, 0.f};
        #pragma unroll 4
        for (int s = 0; s < 32; ++s) {
            int r = rgrp + 4 * s;
            float w = sP[r];
            float4 ev = *(const float4*)(encb + (size_t)r * D_ + colg * 4);
            c4.x += w * ev.x; c4.y += w * ev.y;
            c4.z += w * ev.z; c4.w += w * ev.w;
        }
        float4* red4 = (float4*)sA;             // reuse LDS (frags dead)
        red4[tid] = c4;
        __syncthreads();
        if (rgrp == 0) {
            float4 a0 = red4[colg], a1 = red4[colg + 128];
            float4 a2 = red4[colg + 256], a3 = red4[colg + 384];
            float4 o;
            o.x = a0.x + a1.x + a2.x + a3.x;
            o.y = a0.y + a1.y + a2.y + a3.y;
            o.z = a0.z + a1.z + a2.z + a3.z;
            o.w = a0.w + a1.w + a2.w + a3.w;
            ((float4*)(ws + WS_PCTX))[tile * 128 + colg] = o;
        }

        // ---- arrival: release writes, bump batch counter; last block of the
        // batch will run its finalize (deferred to after the 2nd tile).
        __threadfence();
        __syncthreads();        // also protects sA reuse by next tile staging
        if (tid == 0) sLastFlag = (atomicAdd(&cnt[b], 1) == 31);
        __syncthreads();
        if (sLastFlag) finBatch[tt] = b;

        tile += 512;
    }

    // ---- fused finalize for any batch this block completed last
    #pragma unroll
    for (int q = 0; q < 2; ++q) {
        int fb = finBatch[q];
        if (fb < 0) continue;                  // block-uniform
        __threadfence();                       // acquire side
        float* sm     = &sScoreP[0][0];
        float* sl     = &sScoreP[0][32];
        float* sscale = &sScoreP[0][64];
        __syncthreads();                       // scratch handoff
        const float2* mlp = ((const float2*)(ws + WS_ML)) + fb * 32;
        if (tid < 32) {
            float2 vml = mlp[tid];
            sm[tid] = vml.x; sl[tid] = vml.y;
        }
        __syncthreads();
        float m = -1e30f;
        #pragma unroll
        for (int i = 0; i < 32; ++i) m = fmaxf(m, sm[i]);
        float l = 0.f;
        #pragma unroll
        for (int i = 0; i < 32; ++i) l += sl[i] * expf(sm[i] - m);
        float inv = 1.0f / l;
        if (tid < 32) sscale[tid] = expf(sm[tid] - m) * inv;
        __syncthreads();
        // weights: 4096, 8 per thread (one tile per group of 16 threads)
        {
            const float4* pb = (const float4*)((const float*)(ws + WS_P) + (size_t)fb * T_);
            float4* wb = (float4*)(out_w + (size_t)fb * T_);
            int t0 = tid * 2;
            float sc = sscale[tid >> 4];
            float4 x = pb[t0], y = pb[t0 + 1];
            x.x *= sc; x.y *= sc; x.z *= sc; x.w *= sc;
            y.x *= sc; y.y *= sc; y.z *= sc; y.w *= sc;
            wb[t0] = x; wb[t0 + 1] = y;
        }
        // context: 512 d, 1 per thread
        {
            const float* pc = (const float*)(ws + WS_PCTX) + (size_t)fb * 32 * D_;
            float c = 0.f;
            #pragma unroll
            for (int i = 0; i < 32; ++i) c += pc[i * D_ + tid] * sscale[i];
            out_ctx[fb * D_ + tid] = c;
        }
    }
}

// ------------------------------------------------------------- launcher -----
extern "C" void kernel_launch(void* const* d_in, const int* in_sizes, int n_in,
                              void* d_out, int out_size, void* d_ws, size_t ws_size,
                              hipStream_t stream) {
    const float* hidden = (const float*)d_in[0];   // (32, 512)
    const float* enc    = (const float*)d_in[1];   // (32, 4096, 512)
    const float* W_attn = (const float*)d_in[2];   // (256, 1024)
    const float* b_attn = (const float*)d_in[3];   // (256,)
    const float* v      = (const float*)d_in[4];   // (256,)
    float* out = (float*)d_out;                    // context(16384) ++ weights(131072)
    unsigned char* ws = (unsigned char*)d_ws;

    prep_kernel<<<64, 256, 0, stream>>>(hidden, W_attn, b_attn, ws);
    gemm_scores_kernel<<<512, 512, 0, stream>>>(enc, ws, v, out, out + B_ * D_);
}

// Round 6
// 418.957 us; speedup vs baseline: 2.1815x; 2.1815x over previous
//
// R6: exact revert to R4 (verified 419.6 us). R5's persistent+fused structure
// caused scratch spills (VGPR 64, 216 MB scratch writes, gemm 668 us) — falsified.
#include <hip/hip_runtime.h>
#include <hip/hip_bf16.h>
#include <math.h>

#define B_  32
#define T_  4096
#define H_  256
#define D_  512

// ws layout (bytes):
//   pre   : float [32*256]        @ 0       (h_proj + b_attn)
//   we_hi : ushort[256*512]       @ 32768   (bf16 W_e, per-BK-tile + XOR-swizzled)
//   p     : float [32*4096]       @ 294912  (exp(s - m_blk) per row)
//   ml    : float2[1024]          @ 819200  (per-tile m_blk, l_blk)
//   pctx  : float [1024*512]      @ 827392  (per-tile partial context)
#define WS_PRE    0
#define WS_WEHI   32768
#define WS_P      294912
#define WS_ML     819200
#define WS_PCTX   827392

using short8  = __attribute__((ext_vector_type(8))) short;
using float4v = __attribute__((ext_vector_type(4))) float;

// RNE f32->bf16 pair pack (v_cvt_pk_bf16_f32)
__device__ __forceinline__ unsigned cvt2_bf16(float lo, float hi) {
    union { __hip_bfloat162 h; unsigned u; } cv;
    cv.h = __float22bfloat162_rn(make_float2(lo, hi));
    return cv.u;
}
__device__ __forceinline__ short8 cvt8_bf16(const float* a) {
    union { unsigned u[4]; short8 s; } r;
    r.u[0] = cvt2_bf16(a[0], a[1]);
    r.u[1] = cvt2_bf16(a[2], a[3]);
    r.u[2] = cvt2_bf16(a[4], a[5]);
    r.u[3] = cvt2_bf16(a[6], a[7]);
    return r.s;
}

// tanh(x) = 1 - 2/(e^{2x}+1); |err| ~1e-7, far below the bf16 score floor.
__device__ __forceinline__ float fast_tanh(float x) {
    float e = __expf(2.0f * x);
    return 1.0f - 2.0f * __builtin_amdgcn_rcpf(e + 1.0f);
}

// ---------------------------------------------------------------- prep ------
// blocks 0..31 : h_proj + b_attn
// blocks 32..63: W_e -> bf16, TILED per BK=32 (16KB tiles), XOR-swizzled:
//   (n,k): t=k>>5, quad=(k&31)>>3, e=k&7, slot=quad^((n>>1)&3);
//   dst = t*8192 + n*32 + slot*8 + e. gemm reads fragments directly from
//   this layout (per-wave 1KB contiguous chunks — fully coalesced).
__global__ __launch_bounds__(256)
void prep_kernel(const float* __restrict__ hidden,
                 const float* __restrict__ W_attn,
                 const float* __restrict__ b_attn,
                 unsigned char* __restrict__ ws) {
    int blk = blockIdx.x;
    int tid = threadIdx.x;
    if (blk < 32) {
        int b = blk, h = tid;
        const float4* hv = (const float4*)(hidden + b * D_);
        const float4* wv = (const float4*)(W_attn + (size_t)h * 1024);
        float s = 0.f;
        #pragma unroll 4
        for (int d4 = 0; d4 < D_ / 4; ++d4) {
            float4 a = hv[d4], w = wv[d4];
            s += a.x * w.x + a.y * w.y + a.z * w.z + a.w * w.w;
        }
        ((float*)(ws + WS_PRE))[b * H_ + h] = s + b_attn[h];
    } else {
        int q = (blk - 32) * 256 + tid;            // 0..8191
        unsigned short* whi = (unsigned short*)(ws + WS_WEHI);
        #pragma unroll
        for (int i = 0; i < 4; ++i) {
            int idx4 = q + i * 8192;               // float4 index over [256][128]
            int n = idx4 >> 7, k = (idx4 & 127) << 2;
            int t = k >> 5, kin = k & 31;
            int quad = kin >> 3, e = kin & 7;      // e in {0,4}
            int slot = quad ^ ((n >> 1) & 3);
            float4 w = *(const float4*)(W_attn + (size_t)n * 1024 + 512 + k);
            unsigned lo = cvt2_bf16(w.x, w.y);
            unsigned hi = cvt2_bf16(w.z, w.w);
            unsigned short* dst = whi + t * 8192 + n * 32 + slot * 8 + e;
            *(uint2*)dst = make_uint2(lo, hi);     // 8B aligned (e in {0,4})
        }
    }
}

// ------------------------------- GEMM + tanh + v-dot + local softmax + pctx -
// grid = 1024 blocks (M-tiles of 128), 512 threads (8 waves, 2m x 4n, 64x64).
// BM=128 x BN=256 (full N) x K=512, BK=32.
// A: HBM -> regs (2 sets, 2 slabs ahead) -> bf16 -> LDS (double-buffered).
// B: L2-resident ws tiles -> REGISTERS directly, double-buffered 1 iter
//    ahead (no LDS at all for B). Swizzle makes per-thread slot constant:
//    slot = quad ^ ((l16>>1)&3), so 4 fragment loads/iter share one base.
// One lgkm-only barrier per k-iter, scoped to the A ds_write.
#define BM 128
#define BN 256
#define BK 32
#define LDT 40   // LDS A row stride in ushorts: 80B rows -> 2-way-only alias
#define KIT 16

__global__ __launch_bounds__(512, 4)
void gemm_scores_kernel(const float* __restrict__ enc,
                        unsigned char* __restrict__ ws,
                        const float* __restrict__ v) {
    __shared__ unsigned short sA[2][BM * LDT];     // 20480 B (reused by epilogue)
    __shared__ float sScoreP[4][BM];               // per-wn partial scores
    __shared__ float sP[BM];
    __shared__ float sRed[4];

    const float*          pre = (const float*)(ws + WS_PRE);
    const unsigned short* weh = (const unsigned short*)(ws + WS_WEHI);

    int tid = threadIdx.x;
    int m0  = blockIdx.x * BM;
    int b   = m0 >> 12;

    // A staging: rowA consecutive within a wave -> contiguous LDS writes
    int rowA = tid & 127, cgA = tid >> 7;          // 4 col-groups of 8 floats
    const float* gA = enc + (size_t)(m0 + rowA) * D_ + cgA * 8;

    int wave = tid >> 6, lane = tid & 63;
    int wm = wave & 1, wn = wave >> 1;             // 2 x 4 waves, 64x64 tiles
    int quad = lane >> 4, l16 = lane & 15;

    // B fragment base: c = wn*64 + j*16 + l16; addr = c*32 + slot*8 ushorts
    // with slot = quad ^ ((c>>1)&3) = quad ^ ((l16>>1)&3)  (j,wn-independent)
    int slotB = quad ^ ((l16 >> 1) & 3);
    const unsigned short* bBase = weh + (wn * 64 + l16) * 32 + slotB * 8;

    float4v acc[4][4] = {};

    float aX[8], aY[8];                            // two A prefetch sets
    short8 bhA[4], bhB[4];                         // two B fragment sets

    // ---- preamble: slab0 -> LDS buf0, tile0 -> bhA; issue slab1/tile1
    {
        const float4* p0 = (const float4*)gA;
        float4 x0 = p0[0], x1 = p0[1];
        #pragma unroll
        for (int j = 0; j < 4; ++j)
            bhA[j] = *(const short8*)(bBase + j * 512);
        const float4* p1 = (const float4*)(gA + BK);
        float4 y0 = p1[0], y1 = p1[1];
        #pragma unroll
        for (int j = 0; j < 4; ++j)
            bhB[j] = *(const short8*)(bBase + 8192 + j * 512);

        float tmp[8];
        *(float4*)tmp = x0; *(float4*)(tmp + 4) = x1;
        *(short8*)&sA[0][rowA * LDT + cgA * 8] = cvt8_bf16(tmp);
        *(float4*)aY = y0; *(float4*)(aY + 4) = y1;
    }
    __builtin_amdgcn_s_waitcnt(0xc07f);   // lgkmcnt(0) only
    __builtin_amdgcn_s_barrier();

    // One k-step. Bcur holds tile kk (loaded last iter); Bnxt <- tile kk+1.
    // Acons holds slab kk+1 (written to LDS this iter); Aload <- slab kk+2.
#define K_STEP(kk, CUR, NXT, Acons, Aload, Bcur, Bnxt)                        \
    {                                                                         \
        if ((kk) + 1 < KIT) {                                                 \
            const unsigned short* pb = bBase + ((kk) + 1) * 8192;             \
            Bnxt[0] = *(const short8*)(pb);                                   \
            Bnxt[1] = *(const short8*)(pb + 512);                             \
            Bnxt[2] = *(const short8*)(pb + 1024);                            \
            Bnxt[3] = *(const short8*)(pb + 1536);                            \
        }                                                                     \
        if ((kk) + 2 < KIT) {                                                 \
            const float4* pa = (const float4*)(gA + ((kk) + 2) * BK);         \
            *(float4*)(Aload) = pa[0]; *(float4*)((Aload) + 4) = pa[1];       \
        }                                                                     \
        short8 ah[4];                                                         \
        _Pragma("unroll")                                                     \
        for (int i = 0; i < 4; ++i) {                                         \
            int r = wm * 64 + i * 16 + l16;                                   \
            ah[i] = *(const short8*)&sA[CUR][r * LDT + quad * 8];             \
        }                                                                     \
        _Pragma("unroll")                                                     \
        for (int i = 0; i < 4; ++i)                                           \
            _Pragma("unroll")                                                 \
            for (int j = 0; j < 4; ++j)                                       \
                acc[i][j] = __builtin_amdgcn_mfma_f32_16x16x32_bf16(          \
                    ah[i], Bcur[j], acc[i][j], 0, 0, 0);                      \
        if ((kk) + 1 < KIT) {                                                 \
            *(short8*)&sA[NXT][rowA * LDT + cgA * 8] = cvt8_bf16(Acons);      \
            __builtin_amdgcn_s_waitcnt(0xc07f);                               \
            __builtin_amdgcn_s_barrier();                                     \
        }                                                                     \
    }

    for (int kt = 0; kt < 8; ++kt) {
        K_STEP(2 * kt,     0, 1, aY, aX, bhA, bhB)
        K_STEP(2 * kt + 1, 1, 0, aX, aY, bhB, bhA)
    }
#undef K_STEP

    // ---- scores: energy = tanh(acc + pre[b][n]); rowsum += energy * v[n]
    float rowsum[4][4] = {};
    #pragma unroll
    for (int j = 0; j < 4; ++j) {
        int n = wn * 64 + j * 16 + l16;
        float pv = pre[b * H_ + n];
        float vv = v[n];
        #pragma unroll
        for (int i = 0; i < 4; ++i)
            #pragma unroll
            for (int r = 0; r < 4; ++r)
                rowsum[i][r] += fast_tanh(acc[i][j][r] + pv) * vv;
    }
    #pragma unroll
    for (int i = 0; i < 4; ++i)
        #pragma unroll
        for (int r = 0; r < 4; ++r) {
            float s = rowsum[i][r];
            s += __shfl_xor(s, 1);
            s += __shfl_xor(s, 2);
            s += __shfl_xor(s, 4);
            s += __shfl_xor(s, 8);
            rowsum[i][r] = s;
        }
    if (l16 == 0) {
        #pragma unroll
        for (int i = 0; i < 4; ++i)
            #pragma unroll
            for (int r = 0; r < 4; ++r) {
                int row = wm * 64 + i * 16 + quad * 4 + r;
                sScoreP[wn][row] = rowsum[i][r];   // no atomics: unique writer
            }
    }
    __syncthreads();

    // ---- local softmax over the 128 rows
    float sval = 0.f;
    if (tid < 128) {
        sval = sScoreP[0][tid] + sScoreP[1][tid]
             + sScoreP[2][tid] + sScoreP[3][tid];
        float m = sval;
        #pragma unroll
        for (int off = 32; off; off >>= 1) m = fmaxf(m, __shfl_xor(m, off));
        if (lane == 0) sRed[wave] = m;
    }
    __syncthreads();
    float m_blk = fmaxf(sRed[0], sRed[1]);
    if (tid < 128) {
        float p = expf(sval - m_blk);
        sP[tid] = p;
        ((float*)(ws + WS_P))[m0 + tid] = p;
        float l = p;
        #pragma unroll
        for (int off = 32; off; off >>= 1) l += __shfl_xor(l, off);
        if (lane == 0) sRed[2 + wave] = l;
    }
    __syncthreads();
    if (tid == 0) {
        float2 ml = make_float2(m_blk, sRed[2] + sRed[3]);
        ((float2*)(ws + WS_ML))[blockIdx.x] = ml;
    }

    // ---- partial context: re-read own slab (L3-hot), weight by p
    int colg = tid & 127, rgrp = tid >> 7;     // 128 d-groups x 4 rows in flight
    const float* encb = enc + (size_t)m0 * D_;
    float4 c4 = {0.f, 0.f, 0.f, 0.f};
    #pragma unroll 4
    for (int s = 0; s < 32; ++s) {
        int r = rgrp + 4 * s;
        float w = sP[r];
        float4 ev = *(const float4*)(encb + (size_t)r * D_ + colg * 4);
        c4.x += w * ev.x; c4.y += w * ev.y;
        c4.z += w * ev.z; c4.w += w * ev.w;
    }
    float4* red4 = (float4*)sA;                 // reuse LDS (frags long dead)
    red4[tid] = c4;
    __syncthreads();
    if (rgrp == 0) {
        float4 a0 = red4[colg], a1 = red4[colg + 128];
        float4 a2 = red4[colg + 256], a3 = red4[colg + 384];
        float4 o;
        o.x = a0.x + a1.x + a2.x + a3.x;
        o.y = a0.y + a1.y + a2.y + a3.y;
        o.z = a0.z + a1.z + a2.z + a3.z;
        o.w = a0.w + a1.w + a2.w + a3.w;
        ((float4*)(ws + WS_PCTX))[blockIdx.x * 128 + colg] = o;
    }
}

// ------------------------------------------------------------ finalize ------
// one block per batch: combine 32 tile partials, write weights + context.
__global__ __launch_bounds__(512)
void finalize_kernel(const unsigned char* __restrict__ ws,
                     float* __restrict__ out_ctx,
                     float* __restrict__ out_w) {
    __shared__ float sm[32], sl[32], sscale[32];
    int b = blockIdx.x, tid = threadIdx.x;
    const float2* ml  = ((const float2*)(ws + WS_ML)) + b * 32;
    if (tid < 32) {
        float2 v = ml[tid];
        sm[tid] = v.x; sl[tid] = v.y;
    }
    __syncthreads();
    float m = -1e30f;
    #pragma unroll
    for (int i = 0; i < 32; ++i) m = fmaxf(m, sm[i]);
    float l = 0.f;
    #pragma unroll
    for (int i = 0; i < 32; ++i) l += sl[i] * expf(sm[i] - m);
    float inv = 1.0f / l;
    if (tid < 32) sscale[tid] = expf(sm[tid] - m) * inv;
    __syncthreads();

    // weights: 4096 per batch, 8 per thread (same tile per group of 8)
    {
        const float4* pb = (const float4*)((const float*)(ws + WS_P) + (size_t)b * T_);
        float4* wb = (float4*)(out_w + (size_t)b * T_);
        int t0 = tid * 2;                 // float4 index; tile = (tid*8)>>7
        float sc = sscale[tid >> 4];
        float4 x = pb[t0], y = pb[t0 + 1];
        x.x *= sc; x.y *= sc; x.z *= sc; x.w *= sc;
        y.x *= sc; y.y *= sc; y.z *= sc; y.w *= sc;
        wb[t0] = x; wb[t0 + 1] = y;
    }
    // context: 512 d per batch, 1 per thread
    {
        const float* pc = (const float*)(ws + WS_PCTX) + (size_t)b * 32 * D_;
        float c = 0.f;
        #pragma unroll
        for (int i = 0; i < 32; ++i) c += pc[i * D_ + tid] * sscale[i];
        out_ctx[b * D_ + tid] = c;
    }
}

// ------------------------------------------------------------- launcher -----
extern "C" void kernel_launch(void* const* d_in, const int* in_sizes, int n_in,
                              void* d_out, int out_size, void* d_ws, size_t ws_size,
                              hipStream_t stream) {
    const float* hidden = (const float*)d_in[0];   // (32, 512)
    const float* enc    = (const float*)d_in[1];   // (32, 4096, 512)
    const float* W_attn = (const float*)d_in[2];   // (256, 1024)
    const float* b_attn = (const float*)d_in[3];   // (256,)
    const float* v      = (const float*)d_in[4];   // (256,)
    float* out = (float*)d_out;                    // context(16384) ++ weights(131072)
    unsigned char* ws = (unsigned char*)d_ws;

    prep_kernel<<<64, 256, 0, stream>>>(hidden, W_attn, b_attn, ws);
    gemm_scores_kernel<<<T_ * B_ / BM, 512, 0, stream>>>(enc, ws, v);
    finalize_kernel<<<B_, 512, 0, stream>>>(ws, out, out + B_ * D_);
}